// Round 4
// baseline (1452.778 us; speedup 1.0000x reference)
//
#include <hip/hip_runtime.h>
#include <cstdint>

constexpr int kB = 16;
constexpr int kL = 64;
constexpr int kD = 768;
constexpr int kE = 100000;
constexpr int kR = 200;
constexpr int kT = 1000000;
constexpr size_t kEB = (size_t)kE * 16;
constexpr int kEBq = kE * 4;   // float4 count of an [E,16] array

// ---------------- init: transpose heads/er to [E,16], zero state ----------------
__global__ void __launch_bounds__(256) k_init(const float* __restrict__ heads,
        const float* __restrict__ er, float* __restrict__ headsT, float* __restrict__ erT,
        float* __restrict__ escT, int* __restrict__ cnt, unsigned* __restrict__ rmax,
        float* __restrict__ ssum, float* __restrict__ hsum) {
    int tid = blockIdx.x * blockDim.x + threadIdx.x;
    int gsz = gridDim.x * blockDim.x;
    if (tid < 96) { rmax[tid] = 0u; ssum[tid] = 0.f; }
    if (tid < 16) hsum[tid] = 0.f;
    float4 z4 = make_float4(0.f, 0.f, 0.f, 0.f);
    float4* esc4 = (float4*)escT;
    for (int i = tid; i < kEBq; i += gsz) esc4[i] = z4;
    for (int i = tid; i < kE; i += gsz) cnt[i] = 0;
    const float4* h4 = (const float4*)heads;
    const float4* r4 = (const float4*)er;
    for (int q = tid; q < kE / 4; q += gsz) {
        float hv[16][4], rv[16][4];
#pragma unroll
        for (int b = 0; b < 16; b++) {
            float4 h = h4[b * (kE / 4) + q];
            float4 r = r4[b * (kE / 4) + q];
            hv[b][0] = h.x; hv[b][1] = h.y; hv[b][2] = h.z; hv[b][3] = h.w;
            rv[b][0] = r.x; rv[b][1] = r.y; rv[b][2] = r.z; rv[b][3] = r.w;
        }
        float4* oh = (float4*)headsT + (size_t)q * 16;
        float4* orr = (float4*)erT + (size_t)q * 16;
#pragma unroll
        for (int u = 0; u < 4; u++) {
#pragma unroll
            for (int c = 0; c < 4; c++) {
                oh[u * 4 + c] = make_float4(hv[4*c][u], hv[4*c+1][u], hv[4*c+2][u], hv[4*c+3][u]);
                orr[u * 4 + c] = make_float4(rv[4*c][u], rv[4*c+1][u], rv[4*c+2][u], rv[4*c+3][u]);
            }
        }
    }
}

// ---------------- CSR build ----------------
__global__ void k_hist(const int* __restrict__ obj, int* __restrict__ cnt) {
    int i = blockIdx.x * blockDim.x + threadIdx.x;
    int st = gridDim.x * blockDim.x;
    for (; i < kT; i += st) atomicAdd(&cnt[obj[i]], 1);
}

__global__ void k_scan1(const int* __restrict__ cnt, int* __restrict__ row, int* __restrict__ bsum) {
    __shared__ int s[512];
    int o = blockIdx.x * 512 + threadIdx.x;
    int v = (o < kE) ? cnt[o] : 0;
    s[threadIdx.x] = v;
    __syncthreads();
    for (int off = 1; off < 512; off <<= 1) {
        int t = (threadIdx.x >= off) ? s[threadIdx.x - off] : 0;
        __syncthreads();
        s[threadIdx.x] += t;
        __syncthreads();
    }
    if (o < kE) row[o + 1] = s[threadIdx.x];
    if (threadIdx.x == 511) bsum[blockIdx.x] = s[511];
}

// scan3 with the 196-entry block-sum scan done redundantly per block (kills k_scan2)
__global__ void k_scan3(const int* __restrict__ cnt, int* __restrict__ row,
                        int* __restrict__ fill, const int* __restrict__ bsum) {
    __shared__ int s[256];
    int t = threadIdx.x;
    const int nb = (kE + 511) / 512;   // 196
    int v = (t < nb) ? bsum[t] : 0;
    s[t] = v;
    __syncthreads();
    for (int off = 1; off < 256; off <<= 1) {
        int x = (t >= off) ? s[t - off] : 0;
        __syncthreads();
        s[t] += x;
        __syncthreads();
    }
    int o = blockIdx.x * 256 + t;
    if (o == 0) row[0] = 0;
    if (o < kE) {
        int blk = o / 512;
        int pre = (blk == 0) ? 0 : s[blk - 1];
        int incl = row[o + 1] + pre;
        row[o + 1] = incl;
        fill[o] = incl - cnt[o];
    }
}

__global__ void k_scatter(const int* __restrict__ subj, const int* __restrict__ rel,
                          const int* __restrict__ obj, int* __restrict__ fill,
                          int2* __restrict__ sr) {
    int i = blockIdx.x * blockDim.x + threadIdx.x;
    int st = gridDim.x * blockDim.x;
    for (; i < kT; i += st) {
        int o = obj[i];
        int p = atomicAdd(&fill[o], 1);
        sr[p] = make_int2(subj[i], rel[i]);
    }
}

// ---------------- small dense: qem (i=0) and cq (i=1..6), float4 over d ----------------
__global__ void __launch_bounds__(192) k_dense(const float* __restrict__ q,
        const float* __restrict__ mw, const float* __restrict__ mb,
        const float* __restrict__ sw, const float* __restrict__ sb,
        float* __restrict__ cq) {
    int tid = threadIdx.x;
    int b = blockIdx.x, i = blockIdx.y;
    const float* W    = (i == 0) ? mw : sw + (size_t)(i - 1) * kD * kD;
    const float* bias = (i == 0) ? mb : sb + (size_t)(i - 1) * kD;
    const float* qr   = q + (size_t)b * kD;
    const float4* W4 = (const float4*)W;
    float4 acc = ((const float4*)bias)[tid];
#pragma unroll 4
    for (int k = 0; k < kD; k++) {
        float qk = qr[k];
        float4 wv = W4[k * 192 + tid];
        acc.x += qk * wv.x; acc.y += qk * wv.y; acc.z += qk * wv.z; acc.w += qk * wv.w;
    }
    if (i > 0) { acc.x = tanhf(acc.x); acc.y = tanhf(acc.y); acc.z = tanhf(acc.z); acc.w = tanhf(acc.w); }
    ((float4*)cq)[((size_t)i * 16 + b) * 192 + tid] = acc;
}

// ---------------- hop attention (layout hopL[(w*3+t)*16+b]) ----------------
__global__ void __launch_bounds__(192) k_hop(const float* __restrict__ q,
        const float* __restrict__ hw, const float* __restrict__ hb,
        float* __restrict__ hopL) {
    int w = blockIdx.x, b = blockIdx.y, t = threadIdx.x;
    __shared__ float red[3][192];
    const float4* q4 = (const float4*)(q + (size_t)b * kD);
    float4 qv = q4[t];
    const float* hp = hw + ((size_t)w * kD + 4 * t) * 3;
    float p[3];
#pragma unroll
    for (int s = 0; s < 3; s++)
        p[s] = qv.x * hp[s] + qv.y * hp[3 + s] + qv.z * hp[6 + s] + qv.w * hp[9 + s];
#pragma unroll
    for (int s = 0; s < 3; s++) red[s][t] = p[s];
    __syncthreads();
    for (int off = 96; off >= 3; off >>= 1) {
        if (t < off) {
#pragma unroll
            for (int s = 0; s < 3; s++) red[s][t] += red[s][t + off];
        }
        __syncthreads();
    }
    if (t == 0) {
        float lg[3];
#pragma unroll
        for (int s = 0; s < 3; s++) lg[s] = red[s][0] + red[s][1] + red[s][2] + hb[w * 3 + s];
        float mx = fmaxf(lg[0], fmaxf(lg[1], lg[2]));
        float e0 = expf(lg[0] - mx), e1 = expf(lg[1] - mx), e2 = expf(lg[2] - mx);
        float z = e0 + e1 + e2;
        hopL[(w * 3 + 0) * 16 + b] = e0 / z;
        hopL[(w * 3 + 1) * 16 + b] = e1 / z;
        hopL[(w * 3 + 2) * 16 + b] = e2 / z;
    }
}

// ---------------- per-step context + rel distribution -> wrT ----------------
__global__ void __launch_bounds__(256) k_ctx(const float* __restrict__ cq,
        const float* __restrict__ qwh, const int* __restrict__ mask,
        const float* __restrict__ rw, const float* __restrict__ rb,
        const float* __restrict__ rimp, const float* __restrict__ temp,
        float* __restrict__ wrT) {
    int i = blockIdx.x, b = blockIdx.y, w = i / 3;
    __shared__ float red[64][4];
    __shared__ float dist[64];
    __shared__ float ctx[768];
    __shared__ float rl[200];
    __shared__ float tbuf[8];
    int tid = threadIdx.x;
    const float4* c4 = (const float4*)(cq + ((size_t)(i + 1) * 16 + b) * kD);
    const float4* qh4 = (const float4*)(qwh + (size_t)b * kL * kD);
    {
        int l = tid >> 2, part = tid & 3;
        float a = 0.f;
        for (int u = 0; u < 48; u++) {
            float4 qv = qh4[l * 192 + part * 48 + u];
            float4 cv = c4[part * 48 + u];
            a += qv.x * cv.x + qv.y * cv.y + qv.z * cv.z + qv.w * cv.w;
        }
        red[l][part] = a;
    }
    __syncthreads();
    if (tid < 64) {
        float lg = (red[tid][0] + red[tid][1] + red[tid][2] + red[tid][3]) / temp[0];
        float mx = lg;
        for (int o = 32; o > 0; o >>= 1) mx = fmaxf(mx, __shfl_xor(mx, o));
        float e = expf(lg - mx);
        float z = e;
        for (int o = 32; o > 0; o >>= 1) z += __shfl_xor(z, o);
        float p = e / z * (float)mask[b * kL + tid];
        float s = p;
        for (int o = 32; o > 0; o >>= 1) s += __shfl_xor(s, o);
        dist[tid] = p / (s + 1e-6f);
    }
    __syncthreads();
    if (tid < 192) {
        float4 a = make_float4(0.f, 0.f, 0.f, 0.f);
        for (int l = 0; l < 64; l++) {
            float dl = dist[l];
            float4 qv = qh4[l * 192 + tid];
            a.x += dl * qv.x; a.y += dl * qv.y; a.z += dl * qv.z; a.w += dl * qv.w;
        }
        ((float4*)ctx)[tid] = a;
    }
    __syncthreads();
    if (tid < kR) {
        float a = rb[w * kR + tid];
        const float* Wr = rw + (size_t)w * kD * kR;
#pragma unroll 4
        for (int d = 0; d < kD; d++) a += ctx[d] * Wr[(size_t)d * kR + tid];
        rl[tid] = a;
    }
    __syncthreads();
    {
        float v = (tid < kR) ? rl[tid] : -1e30f;
        float mx = v;
        for (int o = 32; o > 0; o >>= 1) mx = fmaxf(mx, __shfl_xor(mx, o));
        if ((tid & 63) == 0) tbuf[tid >> 6] = mx;
        __syncthreads();
        mx = fmaxf(fmaxf(tbuf[0], tbuf[1]), fmaxf(tbuf[2], tbuf[3]));
        float e = expf(v - mx);
        float z = e;
        for (int o = 32; o > 0; o >>= 1) z += __shfl_xor(z, o);
        if ((tid & 63) == 0) tbuf[4 + (tid >> 6)] = z;
        __syncthreads();
        z = tbuf[4] + tbuf[5] + tbuf[6] + tbuf[7];
        if (tid < kR) wrT[((size_t)i * kR + tid) * 16 + b] = (e / z) * rimp[tid];
    }
}

// ---------------- direct matching v5 ----------------
// Tile: 64 entities x 24 float4 (pad 25 -> compute-read lane stride 100 floats = 4 mod 32,
// conflict-free b128). k split over the 4 waves via readfirstlane -> q stays scalar (s_load).
__global__ void __launch_bounds__(256, 4) k_direct(const float4* __restrict__ emb4,
        const float4* __restrict__ q4, const float4* __restrict__ headsT4,
        float4* __restrict__ directT4, float4* __restrict__ enhU4,
        float* __restrict__ hsum) {
    __shared__ float4 tile[64 * 25];       // 25600 B, reused as reduction buffer
    const int t = threadIdx.x;
    const int l = t & 63;
    const int wu = __builtin_amdgcn_readfirstlane(t >> 6);   // wave id 0..3, scalar
    const int e0 = blockIdx.x * 64;
    float acc[16];
#pragma unroll
    for (int b = 0; b < 16; b++) acc[b] = 0.f;

    for (int c = 0; c < 8; c++) {          // 8 chunks of 24 float4 cols
        __syncthreads();
#pragma unroll
        for (int i = 0; i < 6; i++) {      // 1536 float4 loads, 6 per thread
            int idx = i * 256 + t;
            int r = idx / 24, col = idx - r * 24;
            int ge = e0 + r;
            float4 v = make_float4(0.f, 0.f, 0.f, 0.f);
            if (ge < kE) v = emb4[(size_t)ge * 192 + c * 24 + col];
            tile[r * 25 + col] = v;
        }
        __syncthreads();
#pragma unroll
        for (int j = 0; j < 6; j++) {      // this wave's 6 k-positions
            float4 ev = tile[l * 25 + wu * 6 + j];
            int kq = c * 24 + wu * 6 + j;  // scalar
#pragma unroll
            for (int b = 0; b < 16; b++) {
                float4 qv = q4[b * 192 + kq];   // s_load broadcast
                acc[b] += ev.x * qv.x + ev.y * qv.y + ev.z * qv.z + ev.w * qv.w;
            }
        }
    }
    // cross-wave reduction: red[(w*64+l)*20 + b], stride 20 floats (16B aligned, conflict-free)
    __syncthreads();
    float* red = (float*)tile;
    float4* red4 = (float4*)tile;
#pragma unroll
    for (int c4 = 0; c4 < 4; c4++)
        red4[((wu * 64 + l) * 5) + c4] = make_float4(acc[c4*4], acc[c4*4+1], acc[c4*4+2], acc[c4*4+3]);
    __syncthreads();
    // epilogue: wave w handles b-quad w for all 64 rows
    const int bq = t >> 6;
    const int r = t & 63;
    const int ge = e0 + r;
    const float invs = 0.03608439182435161f; // 1/sqrt(768)
    float4 enh = make_float4(0.f, 0.f, 0.f, 0.f);
    if (ge < kE) {
        float d[4];
#pragma unroll
        for (int bb = 0; bb < 4; bb++) {
            float x = 0.f;
#pragma unroll
            for (int w2 = 0; w2 < 4; w2++) x += red[(w2 * 64 + r) * 20 + bq * 4 + bb];
            d[bb] = 1.f / (1.f + expf(-x * invs));
        }
        directT4[(size_t)ge * 4 + bq] = make_float4(d[0], d[1], d[2], d[3]);
        float4 hq = headsT4[(size_t)ge * 4 + bq];
        enh.x = hq.x * (1.f + 0.3f * d[0]);
        enh.y = hq.y * (1.f + 0.3f * d[1]);
        enh.z = hq.z * (1.f + 0.3f * d[2]);
        enh.w = hq.w * (1.f + 0.3f * d[3]);
        enhU4[(size_t)ge * 4 + bq] = enh;
    }
    // hsum: wave-reduce enh, lane 0 does 4 atomics
    float4 s = enh;
#pragma unroll
    for (int o = 1; o < 64; o <<= 1) {
        s.x += __shfl_xor(s.x, o);
        s.y += __shfl_xor(s.y, o);
        s.z += __shfl_xor(s.z, o);
        s.w += __shfl_xor(s.w, o);
    }
    if (l == 0) {
        atomicAdd(&hsum[bq * 4 + 0], s.x);
        atomicAdd(&hsum[bq * 4 + 1], s.y);
        atomicAdd(&hsum[bq * 4 + 2], s.z);
        atomicAdd(&hsum[bq * 4 + 3], s.w);
    }
}

// ---------------- follow (4 lanes per obj) + fused normacc(prev), 4-edge unroll ----------------
__global__ void __launch_bounds__(256) k_follow(const float4* __restrict__ srcU4,
        const float4* __restrict__ wrT4, const int* __restrict__ row,
        const int2* __restrict__ sr, float4* __restrict__ resOut4,
        unsigned* __restrict__ rmax, const float* __restrict__ rowsum,
        const float4* __restrict__ Un4, const float* __restrict__ nssum,
        const float4* __restrict__ nhc4, const float4* __restrict__ directT4,
        float4* __restrict__ escT4, int do_acc, int nscale) {
    __shared__ float4 wrs[kR * 4];
    __shared__ unsigned umax[16];
    int tid = threadIdx.x;
    if (tid < 16) umax[tid] = 0u;
    {
        const float4* rs4 = (const float4*)rowsum;
        for (int idx = tid; idx < kR * 4; idx += 256) {
            float4 s = rs4[idx & 3];
            float4 wv = wrT4[idx];
            wv.x *= (s.x > 0.f) ? 1.f / s.x : 1.f;
            wv.y *= (s.y > 0.f) ? 1.f / s.y : 1.f;
            wv.z *= (s.z > 0.f) ? 1.f / s.z : 1.f;
            wv.w *= (s.w > 0.f) ? 1.f / s.w : 1.f;
            wrs[idx] = wv;
        }
    }
    __syncthreads();
    int slot = (blockIdx.x * 256 + tid) >> 2;
    int bc = tid & 3;
    float4 res = make_float4(0.f, 0.f, 0.f, 0.f);
    if (slot < kE) {
        int f = slot * 4 + bc;
        if (do_acc) {
            float4 sv = ((const float4*)nssum)[bc];
            float4 si;
            si.x = (sv.x > 0.f) ? 1.f / sv.x : 1.f;
            si.y = (sv.y > 0.f) ? 1.f / sv.y : 1.f;
            si.z = (sv.z > 0.f) ? 1.f / sv.z : 1.f;
            si.w = (sv.w > 0.f) ? 1.f / sv.w : 1.f;
            float4 u = Un4[f];
            float4 hc = nhc4[bc];
            float4 e = escT4[f];
            if (nscale) {
                float4 d = directT4[f];
                e.x += hc.x * u.x * si.x * (1.f + 0.15f * d.x);
                e.y += hc.y * u.y * si.y * (1.f + 0.15f * d.y);
                e.z += hc.z * u.z * si.z * (1.f + 0.15f * d.z);
                e.w += hc.w * u.w * si.w * (1.f + 0.15f * d.w);
            } else {
                e.x += hc.x * u.x * si.x;
                e.y += hc.y * u.y * si.y;
                e.z += hc.z * u.z * si.z;
                e.w += hc.w * u.w * si.w;
            }
            escT4[f] = e;
        }
        int j0 = row[slot], j1 = row[slot + 1];
        float4 a0 = make_float4(0.f, 0.f, 0.f, 0.f);
        float4 a1 = make_float4(0.f, 0.f, 0.f, 0.f);
        float4 a2 = make_float4(0.f, 0.f, 0.f, 0.f);
        float4 a3 = make_float4(0.f, 0.f, 0.f, 0.f);
        int j = j0;
        if ((j & 1) && j < j1) {           // align to even for int4 pair loads
            int2 p = sr[j];
            float4 s0 = srcU4[p.x * 4 + bc];
            float4 w0 = wrs[p.y * 4 + bc];
            a0.x += s0.x * w0.x; a0.y += s0.y * w0.y; a0.z += s0.z * w0.z; a0.w += s0.w * w0.w;
            j++;
        }
        for (; j + 4 <= j1; j += 4) {
            int4 p01 = *(const int4*)(sr + j);
            int4 p23 = *(const int4*)(sr + j + 2);
            float4 s0 = srcU4[p01.x * 4 + bc];
            float4 s1 = srcU4[p01.z * 4 + bc];
            float4 s2 = srcU4[p23.x * 4 + bc];
            float4 s3 = srcU4[p23.z * 4 + bc];
            float4 w0 = wrs[p01.y * 4 + bc];
            float4 w1 = wrs[p01.w * 4 + bc];
            float4 w2 = wrs[p23.y * 4 + bc];
            float4 w3 = wrs[p23.w * 4 + bc];
            a0.x += s0.x * w0.x; a0.y += s0.y * w0.y; a0.z += s0.z * w0.z; a0.w += s0.w * w0.w;
            a1.x += s1.x * w1.x; a1.y += s1.y * w1.y; a1.z += s1.z * w1.z; a1.w += s1.w * w1.w;
            a2.x += s2.x * w2.x; a2.y += s2.y * w2.y; a2.z += s2.z * w2.z; a2.w += s2.w * w2.w;
            a3.x += s3.x * w3.x; a3.y += s3.y * w3.y; a3.z += s3.z * w3.z; a3.w += s3.w * w3.w;
        }
        if (j + 2 <= j1) {
            int4 p01 = *(const int4*)(sr + j);
            float4 s0 = srcU4[p01.x * 4 + bc];
            float4 s1 = srcU4[p01.z * 4 + bc];
            float4 w0 = wrs[p01.y * 4 + bc];
            float4 w1 = wrs[p01.w * 4 + bc];
            a0.x += s0.x * w0.x; a0.y += s0.y * w0.y; a0.z += s0.z * w0.z; a0.w += s0.w * w0.w;
            a1.x += s1.x * w1.x; a1.y += s1.y * w1.y; a1.z += s1.z * w1.z; a1.w += s1.w * w1.w;
            j += 2;
        }
        if (j < j1) {
            int2 p = sr[j];
            float4 s0 = srcU4[p.x * 4 + bc];
            float4 w0 = wrs[p.y * 4 + bc];
            a2.x += s0.x * w0.x; a2.y += s0.y * w0.y; a2.z += s0.z * w0.z; a2.w += s0.w * w0.w;
        }
        res.x = fminf(fmaxf((a0.x + a1.x) + (a2.x + a3.x), 0.f), 1.f);
        res.y = fminf(fmaxf((a0.y + a1.y) + (a2.y + a3.y), 0.f), 1.f);
        res.z = fminf(fmaxf((a0.z + a1.z) + (a2.z + a3.z), 0.f), 1.f);
        res.w = fminf(fmaxf((a0.w + a1.w) + (a2.w + a3.w), 0.f), 1.f);
        resOut4[f] = res;
    }
    for (int o = 4; o < 64; o <<= 1) {
        res.x = fmaxf(res.x, __shfl_xor(res.x, o));
        res.y = fmaxf(res.y, __shfl_xor(res.y, o));
        res.z = fmaxf(res.z, __shfl_xor(res.z, o));
        res.w = fmaxf(res.w, __shfl_xor(res.w, o));
    }
    if ((tid & 63) < 4) {
        atomicMax(&umax[bc * 4 + 0], __float_as_uint(res.x));
        atomicMax(&umax[bc * 4 + 1], __float_as_uint(res.y));
        atomicMax(&umax[bc * 4 + 2], __float_as_uint(res.z));
        atomicMax(&umax[bc * 4 + 3], __float_as_uint(res.w));
    }
    __syncthreads();
    if (tid < 16) atomicMax(&rmax[tid], umax[tid]);
}

// ---------------- combine: /max, residual, *er, row sums (float4) ----------------
__global__ void __launch_bounds__(256) k_combine(float4* __restrict__ res4,
        const float4* __restrict__ uprev4, const float* __restrict__ ssum_prev,
        const float4* __restrict__ erT4, const unsigned* __restrict__ rmax16,
        float* __restrict__ ssum_out, int has_res) {
    __shared__ float ls[16];
    int tid = threadIdx.x;
    if (tid < 16) ls[tid] = 0.f;
    __syncthreads();
    int bc = tid & 3;
    uint4 rm = ((const uint4*)rmax16)[bc];
    float4 mi;
    { float m;
      m = __uint_as_float(rm.x); mi.x = (m > 0.f) ? 1.f / m : 1.f;
      m = __uint_as_float(rm.y); mi.y = (m > 0.f) ? 1.f / m : 1.f;
      m = __uint_as_float(rm.z); mi.z = (m > 0.f) ? 1.f / m : 1.f;
      m = __uint_as_float(rm.w); mi.w = (m > 0.f) ? 1.f / m : 1.f; }
    float4 si = make_float4(1.f, 1.f, 1.f, 1.f);
    if (has_res) {
        float4 s = ((const float4*)ssum_prev)[bc];
        si.x = (s.x > 0.f) ? 1.f / s.x : 1.f;
        si.y = (s.y > 0.f) ? 1.f / s.y : 1.f;
        si.z = (s.z > 0.f) ? 1.f / s.z : 1.f;
        si.w = (s.w > 0.f) ? 1.f / s.w : 1.f;
    }
    float4 su = make_float4(0.f, 0.f, 0.f, 0.f);
    int gsz = gridDim.x * 256;
    for (int f = blockIdx.x * 256 + tid; f < kEBq; f += gsz) {
        float4 v = res4[f];
        v.x *= mi.x; v.y *= mi.y; v.z *= mi.z; v.w *= mi.w;
        if (has_res) {
            float4 u = uprev4[f];
            v.x = 0.7f * v.x + 0.3f * u.x * si.x;
            v.y = 0.7f * v.y + 0.3f * u.y * si.y;
            v.z = 0.7f * v.z + 0.3f * u.z * si.z;
            v.w = 0.7f * v.w + 0.3f * u.w * si.w;
        }
        float4 er = erT4[f];
        v.x *= er.x; v.y *= er.y; v.z *= er.z; v.w *= er.w;
        res4[f] = v;
        su.x += v.x; su.y += v.y; su.z += v.z; su.w += v.w;
    }
    for (int o = 4; o < 64; o <<= 1) {
        su.x += __shfl_xor(su.x, o);
        su.y += __shfl_xor(su.y, o);
        su.z += __shfl_xor(su.z, o);
        su.w += __shfl_xor(su.w, o);
    }
    if ((tid & 63) < 4) {
        atomicAdd(&ls[bc * 4 + 0], su.x);
        atomicAdd(&ls[bc * 4 + 1], su.y);
        atomicAdd(&ls[bc * 4 + 2], su.z);
        atomicAdd(&ls[bc * 4 + 3], su.w);
    }
    __syncthreads();
    if (tid < 16) atomicAdd(&ssum_out[tid], ls[tid]);
}

// ---------------- final: out[b][e] = esc[e][b] + hc5[b]*U5[e][b]*sinv5[b] ----------------
__global__ void k_final(const float4* __restrict__ escT4, const float4* __restrict__ U4,
                        const float* __restrict__ ssum5, const float* __restrict__ hc5,
                        float* __restrict__ out) {
    int e = blockIdx.x * blockDim.x + threadIdx.x;
    if (e >= kE) return;
    float val[16];
#pragma unroll
    for (int c = 0; c < 4; c++) {
        float4 es = escT4[(size_t)e * 4 + c];
        float4 u  = U4[(size_t)e * 4 + c];
        float4 s  = ((const float4*)ssum5)[c];
        float4 h  = ((const float4*)hc5)[c];
        float4 si;
        si.x = (s.x > 0.f) ? 1.f / s.x : 1.f;
        si.y = (s.y > 0.f) ? 1.f / s.y : 1.f;
        si.z = (s.z > 0.f) ? 1.f / s.z : 1.f;
        si.w = (s.w > 0.f) ? 1.f / s.w : 1.f;
        val[4*c+0] = es.x + h.x * u.x * si.x;
        val[4*c+1] = es.y + h.y * u.y * si.y;
        val[4*c+2] = es.z + h.z * u.z * si.z;
        val[4*c+3] = es.w + h.w * u.w * si.w;
    }
#pragma unroll
    for (int b = 0; b < 16; b++) out[(size_t)b * kE + e] = val[b];
}

extern "C" void kernel_launch(void* const* d_in, const int* in_sizes, int n_in,
                              void* d_out, int out_size, void* d_ws, size_t ws_size,
                              hipStream_t stream) {
    const float* heads   = (const float*)d_in[0];
    const float* qemb    = (const float*)d_in[1];
    const float* qwh     = (const float*)d_in[2];
    const int*   amask   = (const int*)d_in[3];
    const float* erange  = (const float*)d_in[4];
    const int*   subj    = (const int*)d_in[5];
    const int*   rel     = (const int*)d_in[6];
    const int*   obj     = (const int*)d_in[7];
    const float* rimp    = (const float*)d_in[8];
    const float* emb     = (const float*)d_in[9];
    const float* mw      = (const float*)d_in[10];
    const float* mb      = (const float*)d_in[11];
    const float* sw      = (const float*)d_in[12];
    const float* sb      = (const float*)d_in[13];
    const float* rw      = (const float*)d_in[14];
    const float* rb      = (const float*)d_in[15];
    const float* hw      = (const float*)d_in[16];
    const float* hb      = (const float*)d_in[17];
    const float* temp    = (const float*)d_in[18];
    float* out = (float*)d_out;

    float* base = (float*)d_ws;
    float* directT = base;
    float* headsT  = directT + kEB;
    float* erT     = headsT + kEB;
    float* enhU    = erT + kEB;
    float* U0      = enhU + kEB;
    float* U1      = U0 + kEB;
    float* escT    = U1 + kEB;
    float* cq      = escT + kEB;                 // 7*16*768
    float* wrT     = cq + (size_t)7 * 16 * kD;   // 6*200*16
    float* hopL    = wrT + (size_t)6 * kR * 16;  // 96
    float* hsum    = hopL + 96;                  // 16
    float* ssum    = hsum + 16;                  // 96
    unsigned* rmax = (unsigned*)(ssum + 96);     // 96
    int* cnt       = (int*)(rmax + 96);          // E
    int* row       = cnt + kE;                   // E+1
    int* fill      = row + kE + 1;               // E
    int* bsum      = fill + kE;                  // 256
    int2* sr = (int2*)(((uintptr_t)(bsum + 256) + 255) & ~(uintptr_t)255);
    float* Ubuf[2] = {U0, U1};

    k_init<<<512, 256, 0, stream>>>(heads, erange, headsT, erT, escT, cnt, rmax, ssum, hsum);
    k_hist<<<512, 256, 0, stream>>>(obj, cnt);
    const int nb = (kE + 511) / 512;
    k_scan1<<<nb, 512, 0, stream>>>(cnt, row, bsum);
    k_scan3<<<(kE + 255) / 256, 256, 0, stream>>>(cnt, row, fill, bsum);
    k_scatter<<<512, 256, 0, stream>>>(subj, rel, obj, fill, sr);

    k_dense<<<dim3(16, 7), 192, 0, stream>>>(qemb, mw, mb, sw, sb, cq);
    k_hop<<<dim3(2, 16), 192, 0, stream>>>(qemb, hw, hb, hopL);
    k_ctx<<<dim3(6, 16), 256, 0, stream>>>(cq, qwh, amask, rw, rb, rimp, temp, wrT);

    k_direct<<<1563, 256, 0, stream>>>((const float4*)emb, (const float4*)cq,
                                       (const float4*)headsT, (float4*)directT,
                                       (float4*)enhU, hsum);

    for (int i = 0; i < 6; i++) {
        int t = i % 3;
        const float* srcU = (t == 0) ? enhU : Ubuf[(i - 1) & 1];
        const float* rowsum = (t == 0) ? hsum : ssum + (i - 1) * 16;
        int do_acc = (i > 0);
        const float* Un = do_acc ? Ubuf[(i - 1) & 1] : enhU;
        const float* nss = do_acc ? ssum + (i - 1) * 16 : hsum;
        const float* nhc = hopL + (do_acc ? (i - 1) * 16 : 0);
        int nscale = do_acc ? ((i - 1) < 3 ? 1 : 0) : 0;
        k_follow<<<1563, 256, 0, stream>>>((const float4*)srcU,
                (const float4*)(wrT + (size_t)i * kR * 16), row, sr,
                (float4*)Ubuf[i & 1], rmax + i * 16, rowsum,
                (const float4*)Un, nss, (const float4*)nhc,
                (const float4*)directT, (float4*)escT, do_acc, nscale);
        k_combine<<<1024, 256, 0, stream>>>((float4*)Ubuf[i & 1],
                (const float4*)(t > 0 ? Ubuf[(i - 1) & 1] : enhU),
                t > 0 ? ssum + (i - 1) * 16 : hsum,
                (const float4*)erT, rmax + i * 16, ssum + i * 16, t > 0 ? 1 : 0);
    }
    k_final<<<(kE + 255) / 256, 256, 0, stream>>>((const float4*)escT,
            (const float4*)Ubuf[1], ssum + 80, hopL + 80, out);
}